// Round 17
// baseline (98.770 us; speedup 1.0000x reference)
//
#include <hip/hip_runtime.h>
#include <math.h>

#define N_TOTAL 8192
#define BATCH   4096
#define DIMS    64
#define P1_BLOCKS 512    // 2048 waves = one 4-row group per wave
#define SEG     8
#define P2_BLOCKS 1088   // live-only: sum_{bc=0}^{127} (bc/8 + 1)

// ws layout (bytes):
//   0       double sqpart[512]       (per-block sum of sq norms)
//   4096    double colpart[512*64]   (per-block col sums, block-major) ->266240
//   266240  float  cs                (exp2 scale)
//   266244  int    cnt2              (pass2 counter, zeroed by scale_kernel)
//   267264  float  partials[1088]
//   276480  float  sq[8192]
//   311296  short  Xh[8192*64]       (bf16, row-major)
// No memset: every slot is written before it is read (cnt2 by scale_kernel).
//
// bf16-only GEMM (no hi/lo compensation): errL2 std ~0.05 -> grand-sum error
// ~5e-7 vs threshold 3.16e-5 (60x margin). Norms/bandwidth stay exact.
// Epilogue on float2 pairs -> packed fp32 (v_pk_*).
// R14 lesson: __threadfence() ONLY on the thread-0 path (per-wave device
// fence = L2 writeback storm, 327 us).

#if defined(__has_builtin)
#if __has_builtin(__builtin_amdgcn_exp2f)
#define EXP2F(x) __builtin_amdgcn_exp2f(x)
#endif
#endif
#ifndef EXP2F
#define EXP2F(x) exp2f(x)
#endif

typedef __attribute__((ext_vector_type(8))) short bf16x8;
typedef __attribute__((ext_vector_type(4))) float f32x4;
typedef __attribute__((ext_vector_type(2))) float f32x2;
typedef __attribute__((ext_vector_type(4))) short s16x4;

__device__ inline short f2bf_rn(float x) {
    unsigned u = __float_as_uint(x);
    unsigned r = (u + 0x7fffu + ((u >> 16) & 1u)) >> 16;
    return (short)r;
}

// pass1: fp32 -> bf16 (once), row sq-norms (exact fp32), per-block col/sq
// partials stored to memory. 512 blocks -> 1 group-iter per wave.
__global__ __launch_bounds__(256) void pass1_kernel(const float* __restrict__ src,
                                                    const float* __restrict__ tgt,
                                                    double* __restrict__ sqpart,
                                                    double* __restrict__ colpart,
                                                    float* __restrict__ sqbuf,
                                                    short* __restrict__ Xh) {
    __shared__ double cred[4][64];
    __shared__ double sred[4];
    const int lane = threadIdx.x & 63;
    const int wv = threadIdx.x >> 6;
    const int sub = lane >> 4;
    const int k4 = (lane & 15) << 2;
    const int gw = blockIdx.x * 4 + wv;
    const int numWaves = P1_BLOCKS * 4;

    double colacc[4] = {0.0, 0.0, 0.0, 0.0};
    double sqacc = 0.0;

    for (int g = gw; g < N_TOTAL / 4; g += numWaves) {
        int r = g * 4 + sub;
        const float* row = (r < BATCH) ? (src + (size_t)r * DIMS)
                                       : (tgt + (size_t)(r - BATCH) * DIMS);
        float4 v = *(const float4*)(row + k4);
        float xs[4] = {v.x, v.y, v.z, v.w};
        s16x4 h;
        float ssum = 0.f;
        #pragma unroll
        for (int i = 0; i < 4; ++i) {
            h[i] = f2bf_rn(xs[i]);
            colacc[i] += (double)xs[i];
            ssum = fmaf(xs[i], xs[i], ssum);
        }
        *(s16x4*)(Xh + (size_t)r * DIMS + k4) = h;
        ssum += __shfl_xor(ssum, 1, 64);
        ssum += __shfl_xor(ssum, 2, 64);
        ssum += __shfl_xor(ssum, 4, 64);
        ssum += __shfl_xor(ssum, 8, 64);
        if ((lane & 15) == 0) { sqbuf[r] = ssum; sqacc += (double)ssum; }
    }
    #pragma unroll
    for (int i = 0; i < 4; ++i) {
        colacc[i] += __shfl_xor(colacc[i], 16, 64);
        colacc[i] += __shfl_xor(colacc[i], 32, 64);
    }
    sqacc += __shfl_xor(sqacc, 16, 64);
    sqacc += __shfl_xor(sqacc, 32, 64);
    if (lane < 16) {
        #pragma unroll
        for (int i = 0; i < 4; ++i) cred[wv][lane * 4 + i] = colacc[i];
    }
    if (lane == 0) sred[wv] = sqacc;
    __syncthreads();
    if (wv == 0) {
        double c = (cred[0][lane] + cred[1][lane]) + (cred[2][lane] + cred[3][lane]);
        colpart[(size_t)blockIdx.x * 64 + lane] = c;     // coalesced store
        if (lane == 0)
            sqpart[blockIdx.x] = (sred[0] + sred[1]) + (sred[2] + sred[3]);
    }
}

// 512 threads (8 waves): reduce 512 per-block partials -> scale; zero cnt2.
__global__ __launch_bounds__(512) void scale_kernel(const double* __restrict__ sqpart,
                                                    const double* __restrict__ colpart,
                                                    float* __restrict__ csp,
                                                    int* __restrict__ cnt2) {
    __shared__ double cred[8][64];
    __shared__ double sred[8];
    const int t = threadIdx.x;
    const int lane = t & 63, w = t >> 6;
    if (t == 0) *cnt2 = 0;

    double colacc = 0.0;
    #pragma unroll 8
    for (int b = w; b < P1_BLOCKS; b += 8)
        colacc += colpart[(size_t)b * 64 + lane];    // coalesced per wave
    cred[w][lane] = colacc;

    double sacc = sqpart[t];                          // 512 threads, 512 values
    #pragma unroll
    for (int off = 32; off > 0; off >>= 1) sacc += __shfl_xor(sacc, off, 64);
    if (lane == 0) sred[w] = sacc;
    __syncthreads();

    if (w == 0) {
        double colsum = ((cred[0][lane] + cred[1][lane]) + (cred[2][lane] + cred[3][lane]))
                      + ((cred[4][lane] + cred[5][lane]) + (cred[6][lane] + cred[7][lane]));
        double vv = colsum * colsum;
        #pragma unroll
        for (int off = 32; off > 0; off >>= 1) vv += __shfl_xor(vv, off, 64);
        if (lane == 0) {
            double sq = ((sred[0] + sred[1]) + (sred[2] + sred[3]))
                      + ((sred[4] + sred[5]) + (sred[6] + sred[7]));
            const double n = (double)N_TOTAL;
            double bw0 = (2.0 * n * sq - 2.0 * vv) / (n * n - n) * 0.25;
            csp[0] = (float)(-1.0 / (bw0 * 0.6931471805599453 * 16.0));
        }
    }
}

// pass2: R16 body (frozen) + finalize fused into the last block
// (R12-proven fenced counter; fence on thread-0 path only).
__global__ __launch_bounds__(512) void pass2_kernel(const short* __restrict__ Xh,
                                                    const float* __restrict__ sqbuf,
                                                    const float* __restrict__ csp,
                                                    float* __restrict__ partials,
                                                    int* __restrict__ cnt2,
                                                    float* __restrict__ out) {
    // decode flat id: band b (bc=8b+q) has 8 bc x (b+1) segments
    const int f = blockIdx.x;
    int b = 0;
    while (4 * (b + 1) * (b + 2) <= f) ++b;          // <=15 steps
    const int rem = f - 4 * b * (b + 1);
    const int q = rem / (b + 1);
    const int bc = 8 * b + q;
    const int seg = rem - q * (b + 1);
    const int r0 = seg * SEG;
    const int r1 = (bc < r0 + SEG - 1) ? bc : r0 + SEG - 1;

    __shared__ __align__(16) short Bh[64][72];
    __shared__ float s_wred[8];
    __shared__ int s_last;

    const int t = threadIdx.x;
    const int lane = t & 63, w = t >> 6;
    const int strip = w & 3, ts = w >> 2;
    const int quad = lane >> 4, lrow = lane & 15;

    // stage B column-tile into LDS: 512 threads, one shot
    {
        int row = t >> 3;            // 0..63
        int c8 = (t & 7) << 3;       // short offset 0..56
        size_t gsrc = (size_t)(bc * 64 + row) * DIMS + c8;
        *(s16x4*)&Bh[row][c8]     = *(const s16x4*)(Xh + gsrc);
        *(s16x4*)&Bh[row][c8 + 4] = *(const s16x4*)(Xh + gsrc + 4);
    }
    const float cs = csp[0];
    const float c2 = -2.f * cs;
    const f32x2 c2v = (f32x2){c2, c2};
    f32x2 sbj[4];
    #pragma unroll
    for (int j = 0; j < 4; ++j) {
        float s = sqbuf[bc * 64 + j * 16 + lrow] * cs;
        sbj[j] = (f32x2){s, s};
    }
    __syncthreads();

    const size_t aoff = (size_t)(strip * 16 + lrow) * DIMS + quad * 8;

    float facc = 0.f;

    for (int r = r0 + ts; r <= r1; r += 2) {
        const size_t abase = (size_t)r * 64 * DIMS + aoff;
        bf16x8 ah0 = *(const bf16x8*)(Xh + abase);
        bf16x8 ah1 = *(const bf16x8*)(Xh + abase + 32);
        float4 csa = *(const float4*)(sqbuf + r * 64 + strip * 16 + quad * 4);

        f32x4 acc[4];
        #pragma unroll
        for (int j = 0; j < 4; ++j) acc[j] = (f32x4){0.f, 0.f, 0.f, 0.f};
        #pragma unroll
        for (int j = 0; j < 4; ++j) {
            const int brow = j * 16 + lrow;
            const int bcol = quad * 8;
            bf16x8 bh0 = *(const bf16x8*)&Bh[brow][bcol];
            bf16x8 bh1 = *(const bf16x8*)&Bh[brow][bcol + 32];
            acc[j] = __builtin_amdgcn_mfma_f32_16x16x32_bf16(ah0, bh0, acc[j], 0, 0, 0);
            acc[j] = __builtin_amdgcn_mfma_f32_16x16x32_bf16(ah1, bh1, acc[j], 0, 0, 0);
        }

        const f32x2 sa01 = (f32x2){csa.x * cs, csa.y * cs};
        const f32x2 sa23 = (f32x2){csa.z * cs, csa.w * cs};
        f32x2 lsum2 = (f32x2){0.f, 0.f};
        #pragma unroll
        for (int j = 0; j < 4; ++j) {
            // t0 = -L2/(16*bw0*ln2) on element pairs (packed fp32)
            f32x2 a01 = (f32x2){acc[j][0], acc[j][1]};
            f32x2 a23 = (f32x2){acc[j][2], acc[j][3]};
            f32x2 t01 = a01 * c2v + (sa01 + sbj[j]);
            f32x2 t23 = a23 * c2v + (sa23 + sbj[j]);
            // 1 exp2 + 4 packed squarings = all 5 bandwidth kernels
            f32x2 e4a = (f32x2){EXP2F(t01[0]), EXP2F(t01[1])};
            f32x2 e4b = (f32x2){EXP2F(t23[0]), EXP2F(t23[1])};
            f32x2 e3a = e4a * e4a, e3b = e4b * e4b;
            f32x2 e2a = e3a * e3a, e2b = e3b * e3b;
            f32x2 e1a = e2a * e2a, e1b = e2b * e2b;
            f32x2 e0a = e1a * e1a, e0b = e1b * e1b;
            lsum2 += ((e0a + e1a) + (e2a + e3a)) + e4a;
            lsum2 += ((e0b + e1b) + (e2b + e3b)) + e4b;
        }
        float lsum = lsum2[0] + lsum2[1];
        float sgn = ((r < 64) == (bc < 64)) ? 1.f : -1.f;
        float wt  = (r == bc) ? 1.f : 2.f;
        facc = fmaf(lsum, sgn * wt, facc);
    }

    #pragma unroll
    for (int off = 32; off > 0; off >>= 1) facc += __shfl_xor(facc, off, 64);
    if (lane == 0) s_wred[w] = facc;
    __syncthreads();
    if (t == 0) {
        partials[f] = ((s_wred[0] + s_wred[1]) + (s_wred[2] + s_wred[3]))
                    + ((s_wred[4] + s_wred[5]) + (s_wred[6] + s_wred[7]));
        __threadfence();                       // thread-0 only (R14 lesson)
        s_last = (atomicAdd(cnt2, 1) == P2_BLOCKS - 1) ? 1 : 0;
    }
    __syncthreads();
    if (s_last) {                              // fused finalize: one block
        __threadfence();
        double acc = 0.0;
        for (int i = t; i < P2_BLOCKS; i += 512)
            acc += (double)atomicAdd(&partials[i], 0.f);   // coherent read
        #pragma unroll
        for (int off = 32; off > 0; off >>= 1) acc += __shfl_xor(acc, off, 64);
        __shared__ double s_red[8];
        if (lane == 0) s_red[w] = acc;
        __syncthreads();
        if (t == 0) {
            double g = ((s_red[0] + s_red[1]) + (s_red[2] + s_red[3]))
                     + ((s_red[4] + s_red[5]) + (s_red[6] + s_red[7]));
            out[0] = (float)(g / ((double)BATCH * (double)BATCH));
        }
    }
}

extern "C" void kernel_launch(void* const* d_in, const int* in_sizes, int n_in,
                              void* d_out, int out_size, void* d_ws, size_t ws_size,
                              hipStream_t stream) {
    const float* src = (const float*)d_in[0];
    const float* tgt = (const float*)d_in[1];
    char* ws = (char*)d_ws;
    double* sqpart  = (double*)ws;
    double* colpart = (double*)(ws + 4096);
    float*  csp     = (float*)(ws + 266240);
    int*    cnt2    = (int*)(ws + 266244);
    float*  parts   = (float*)(ws + 267264);
    float*  sqbuf   = (float*)(ws + 276480);
    short*  Xh      = (short*)(ws + 311296);

    // no memset: every ws slot is written before it is read

    pass1_kernel<<<P1_BLOCKS, 256, 0, stream>>>(src, tgt, sqpart, colpart,
                                                sqbuf, Xh);
    scale_kernel<<<1, 512, 0, stream>>>(sqpart, colpart, csp, cnt2);

    pass2_kernel<<<P2_BLOCKS, 512, 0, stream>>>(Xh, sqbuf, csp, parts,
                                                cnt2, (float*)d_out);
}

// Round 18
// 82.554 us; speedup vs baseline: 1.1964x; 1.1964x over previous
//
#include <hip/hip_runtime.h>
#include <math.h>

#define N_TOTAL 8192
#define BATCH   4096
#define DIMS    64
#define P1_BLOCKS 512    // 2048 waves = one 4-row group per wave (no serial HBM chain)
#define SEG     8
#define P2_BLOCKS 1088   // live-only: sum_{bc=0}^{127} (bc/8 + 1)

// ws layout (bytes):
//   0       double sqpart[512]       (per-block sum of sq norms)
//   4096    double colpart[512*64]   (per-block col sums, block-major) ->266240
//   266240  float  cs                (exp2 scale)
//   267264  float  partials[1088]    ->271616
//   276480  float  sq[8192]          ->309248
//   311296  short  Xh[8192*64]       (bf16, row-major)
// No memset: every slot is written before it is read.
//
// bf16-only GEMM (no hi/lo compensation): errL2 std ~0.05 -> grand-sum error
// ~5e-7 vs threshold 3.16e-5 (60x margin). Norms/bandwidth stay exact.
// Epilogue on float2 pairs -> packed fp32 (v_pk_*).
// R14 lesson: never __threadfence() on the all-threads path (L2 storm).
// R17 lesson: fused finalize via device counter+fence costs +15us vs a
// separate 1-block kernel -- kernel-boundary sync wins at ~1K blocks.

#if defined(__has_builtin)
#if __has_builtin(__builtin_amdgcn_exp2f)
#define EXP2F(x) __builtin_amdgcn_exp2f(x)
#endif
#endif
#ifndef EXP2F
#define EXP2F(x) exp2f(x)
#endif

typedef __attribute__((ext_vector_type(8))) short bf16x8;
typedef __attribute__((ext_vector_type(4))) float f32x4;
typedef __attribute__((ext_vector_type(2))) float f32x2;
typedef __attribute__((ext_vector_type(4))) short s16x4;

__device__ inline short f2bf_rn(float x) {
    unsigned u = __float_as_uint(x);
    unsigned r = (u + 0x7fffu + ((u >> 16) & 1u)) >> 16;
    return (short)r;
}

// pass1: fp32 -> bf16 (once), row sq-norms (exact fp32), per-block col/sq
// partials stored to memory. 512 blocks -> 1 group-iter per wave.
__global__ __launch_bounds__(256) void pass1_kernel(const float* __restrict__ src,
                                                    const float* __restrict__ tgt,
                                                    double* __restrict__ sqpart,
                                                    double* __restrict__ colpart,
                                                    float* __restrict__ sqbuf,
                                                    short* __restrict__ Xh) {
    __shared__ double cred[4][64];
    __shared__ double sred[4];
    const int lane = threadIdx.x & 63;
    const int wv = threadIdx.x >> 6;
    const int sub = lane >> 4;
    const int k4 = (lane & 15) << 2;
    const int gw = blockIdx.x * 4 + wv;
    const int numWaves = P1_BLOCKS * 4;

    double colacc[4] = {0.0, 0.0, 0.0, 0.0};
    double sqacc = 0.0;

    for (int g = gw; g < N_TOTAL / 4; g += numWaves) {
        int r = g * 4 + sub;
        const float* row = (r < BATCH) ? (src + (size_t)r * DIMS)
                                       : (tgt + (size_t)(r - BATCH) * DIMS);
        float4 v = *(const float4*)(row + k4);
        float xs[4] = {v.x, v.y, v.z, v.w};
        s16x4 h;
        float ssum = 0.f;
        #pragma unroll
        for (int i = 0; i < 4; ++i) {
            h[i] = f2bf_rn(xs[i]);
            colacc[i] += (double)xs[i];
            ssum = fmaf(xs[i], xs[i], ssum);
        }
        *(s16x4*)(Xh + (size_t)r * DIMS + k4) = h;
        ssum += __shfl_xor(ssum, 1, 64);
        ssum += __shfl_xor(ssum, 2, 64);
        ssum += __shfl_xor(ssum, 4, 64);
        ssum += __shfl_xor(ssum, 8, 64);
        if ((lane & 15) == 0) { sqbuf[r] = ssum; sqacc += (double)ssum; }
    }
    #pragma unroll
    for (int i = 0; i < 4; ++i) {
        colacc[i] += __shfl_xor(colacc[i], 16, 64);
        colacc[i] += __shfl_xor(colacc[i], 32, 64);
    }
    sqacc += __shfl_xor(sqacc, 16, 64);
    sqacc += __shfl_xor(sqacc, 32, 64);
    if (lane < 16) {
        #pragma unroll
        for (int i = 0; i < 4; ++i) cred[wv][lane * 4 + i] = colacc[i];
    }
    if (lane == 0) sred[wv] = sqacc;
    __syncthreads();
    if (wv == 0) {
        double c = (cred[0][lane] + cred[1][lane]) + (cred[2][lane] + cred[3][lane]);
        colpart[(size_t)blockIdx.x * 64 + lane] = c;     // coalesced store
        if (lane == 0)
            sqpart[blockIdx.x] = (sred[0] + sred[1]) + (sred[2] + sred[3]);
    }
}

// 512 threads (8 waves): parallel reduction of 512 per-block partials -> scale.
__global__ __launch_bounds__(512) void scale_kernel(const double* __restrict__ sqpart,
                                                    const double* __restrict__ colpart,
                                                    float* __restrict__ csp) {
    __shared__ double cred[8][64];
    __shared__ double sred[8];
    const int t = threadIdx.x;
    const int lane = t & 63, w = t >> 6;

    double colacc = 0.0;
    #pragma unroll 8
    for (int b = w; b < P1_BLOCKS; b += 8)
        colacc += colpart[(size_t)b * 64 + lane];    // coalesced per wave
    cred[w][lane] = colacc;

    double sacc = sqpart[t];                          // 512 threads, 512 values
    #pragma unroll
    for (int off = 32; off > 0; off >>= 1) sacc += __shfl_xor(sacc, off, 64);
    if (lane == 0) sred[w] = sacc;
    __syncthreads();

    if (w == 0) {
        double colsum = ((cred[0][lane] + cred[1][lane]) + (cred[2][lane] + cred[3][lane]))
                      + ((cred[4][lane] + cred[5][lane]) + (cred[6][lane] + cred[7][lane]));
        double vv = colsum * colsum;
        #pragma unroll
        for (int off = 32; off > 0; off >>= 1) vv += __shfl_xor(vv, off, 64);
        if (lane == 0) {
            double sq = ((sred[0] + sred[1]) + (sred[2] + sred[3]))
                      + ((sred[4] + sred[5]) + (sred[6] + sred[7]));
            const double n = (double)N_TOTAL;
            double bw0 = (2.0 * n * sq - 2.0 * vv) / (n * n - n) * 0.25;
            csp[0] = (float)(-1.0 / (bw0 * 0.6931471805599453 * 16.0));
        }
    }
}

// pass2: frozen best body. Flat live-only grid of 1088 blocks (band decode).
// 512-thread blocks = 8 waves share one LDS B-tile; per tile-iter: 2 global
// A-loads, 8 LDS b128, 8 MFMA, packed-fp32 exp epilogue.
__global__ __launch_bounds__(512) void pass2_kernel(const short* __restrict__ Xh,
                                                    const float* __restrict__ sqbuf,
                                                    const float* __restrict__ csp,
                                                    float* __restrict__ partials) {
    // decode flat id: band b (bc=8b+q) has 8 bc x (b+1) segments
    const int f = blockIdx.x;
    int b = 0;
    while (4 * (b + 1) * (b + 2) <= f) ++b;          // <=15 steps
    const int rem = f - 4 * b * (b + 1);
    const int q = rem / (b + 1);
    const int bc = 8 * b + q;
    const int seg = rem - q * (b + 1);
    const int r0 = seg * SEG;
    const int r1 = (bc < r0 + SEG - 1) ? bc : r0 + SEG - 1;

    __shared__ __align__(16) short Bh[64][72];
    __shared__ float s_wred[8];

    const int t = threadIdx.x;
    const int lane = t & 63, w = t >> 6;
    const int strip = w & 3, ts = w >> 2;
    const int quad = lane >> 4, lrow = lane & 15;

    // stage B column-tile into LDS: 512 threads, one shot
    {
        int row = t >> 3;            // 0..63
        int c8 = (t & 7) << 3;       // short offset 0..56
        size_t gsrc = (size_t)(bc * 64 + row) * DIMS + c8;
        *(s16x4*)&Bh[row][c8]     = *(const s16x4*)(Xh + gsrc);
        *(s16x4*)&Bh[row][c8 + 4] = *(const s16x4*)(Xh + gsrc + 4);
    }
    const float cs = csp[0];
    const float c2 = -2.f * cs;
    const f32x2 c2v = (f32x2){c2, c2};
    f32x2 sbj[4];
    #pragma unroll
    for (int j = 0; j < 4; ++j) {
        float s = sqbuf[bc * 64 + j * 16 + lrow] * cs;
        sbj[j] = (f32x2){s, s};
    }
    __syncthreads();

    const size_t aoff = (size_t)(strip * 16 + lrow) * DIMS + quad * 8;

    float facc = 0.f;

    for (int r = r0 + ts; r <= r1; r += 2) {
        const size_t abase = (size_t)r * 64 * DIMS + aoff;
        bf16x8 ah0 = *(const bf16x8*)(Xh + abase);
        bf16x8 ah1 = *(const bf16x8*)(Xh + abase + 32);
        float4 csa = *(const float4*)(sqbuf + r * 64 + strip * 16 + quad * 4);

        f32x4 acc[4];
        #pragma unroll
        for (int j = 0; j < 4; ++j) acc[j] = (f32x4){0.f, 0.f, 0.f, 0.f};
        #pragma unroll
        for (int j = 0; j < 4; ++j) {
            const int brow = j * 16 + lrow;
            const int bcol = quad * 8;
            bf16x8 bh0 = *(const bf16x8*)&Bh[brow][bcol];
            bf16x8 bh1 = *(const bf16x8*)&Bh[brow][bcol + 32];
            acc[j] = __builtin_amdgcn_mfma_f32_16x16x32_bf16(ah0, bh0, acc[j], 0, 0, 0);
            acc[j] = __builtin_amdgcn_mfma_f32_16x16x32_bf16(ah1, bh1, acc[j], 0, 0, 0);
        }

        const f32x2 sa01 = (f32x2){csa.x * cs, csa.y * cs};
        const f32x2 sa23 = (f32x2){csa.z * cs, csa.w * cs};
        f32x2 lsum2 = (f32x2){0.f, 0.f};
        #pragma unroll
        for (int j = 0; j < 4; ++j) {
            // t0 = -L2/(16*bw0*ln2) on element pairs (packed fp32)
            f32x2 a01 = (f32x2){acc[j][0], acc[j][1]};
            f32x2 a23 = (f32x2){acc[j][2], acc[j][3]};
            f32x2 t01 = a01 * c2v + (sa01 + sbj[j]);
            f32x2 t23 = a23 * c2v + (sa23 + sbj[j]);
            // 1 exp2 + 4 packed squarings = all 5 bandwidth kernels
            f32x2 e4a = (f32x2){EXP2F(t01[0]), EXP2F(t01[1])};
            f32x2 e4b = (f32x2){EXP2F(t23[0]), EXP2F(t23[1])};
            f32x2 e3a = e4a * e4a, e3b = e4b * e4b;
            f32x2 e2a = e3a * e3a, e2b = e3b * e3b;
            f32x2 e1a = e2a * e2a, e1b = e2b * e2b;
            f32x2 e0a = e1a * e1a, e0b = e1b * e1b;
            lsum2 += ((e0a + e1a) + (e2a + e3a)) + e4a;
            lsum2 += ((e0b + e1b) + (e2b + e3b)) + e4b;
        }
        float lsum = lsum2[0] + lsum2[1];
        float sgn = ((r < 64) == (bc < 64)) ? 1.f : -1.f;
        float wt  = (r == bc) ? 1.f : 2.f;
        facc = fmaf(lsum, sgn * wt, facc);
    }

    #pragma unroll
    for (int off = 32; off > 0; off >>= 1) facc += __shfl_xor(facc, off, 64);
    if (lane == 0) s_wred[w] = facc;
    __syncthreads();
    if (t == 0)
        partials[f] = ((s_wred[0] + s_wred[1]) + (s_wred[2] + s_wred[3]))
                    + ((s_wred[4] + s_wred[5]) + (s_wred[6] + s_wred[7]));
}

__global__ __launch_bounds__(256) void finalize_kernel(const float* __restrict__ partials,
                                                       float* __restrict__ out) {
    __shared__ double s_red[4];
    const int t = threadIdx.x;
    const int lane = t & 63, w = t >> 6;
    double acc = 0.0;
    for (int i = t; i < P2_BLOCKS; i += 256)
        acc += (double)partials[i];
    #pragma unroll
    for (int off = 32; off > 0; off >>= 1) acc += __shfl_xor(acc, off, 64);
    if (lane == 0) s_red[w] = acc;
    __syncthreads();
    if (t == 0) {
        double g = (s_red[0] + s_red[1]) + (s_red[2] + s_red[3]);
        out[0] = (float)(g / ((double)BATCH * (double)BATCH));
    }
}

extern "C" void kernel_launch(void* const* d_in, const int* in_sizes, int n_in,
                              void* d_out, int out_size, void* d_ws, size_t ws_size,
                              hipStream_t stream) {
    const float* src = (const float*)d_in[0];
    const float* tgt = (const float*)d_in[1];
    char* ws = (char*)d_ws;
    double* sqpart  = (double*)ws;
    double* colpart = (double*)(ws + 4096);
    float*  csp     = (float*)(ws + 266240);
    float*  parts   = (float*)(ws + 267264);
    float*  sqbuf   = (float*)(ws + 276480);
    short*  Xh      = (short*)(ws + 311296);

    // no memset: every ws slot is written before it is read

    pass1_kernel<<<P1_BLOCKS, 256, 0, stream>>>(src, tgt, sqpart, colpart,
                                                sqbuf, Xh);
    scale_kernel<<<1, 512, 0, stream>>>(sqpart, colpart, csp);

    pass2_kernel<<<P2_BLOCKS, 512, 0, stream>>>(Xh, sqbuf, csp, parts);

    finalize_kernel<<<1, 256, 0, stream>>>(parts, (float*)d_out);
}

// Round 19
// 81.694 us; speedup vs baseline: 1.2090x; 1.0105x over previous
//
#include <hip/hip_runtime.h>
#include <math.h>

#define N_TOTAL 8192
#define BATCH   4096
#define DIMS    64
#define P1_BLOCKS 512    // 2048 waves = one 4-row group per wave
#define SEG     8
#define P2_BLOCKS 1088   // live-only: sum_{bc=0}^{127} (bc/8 + 1)

// ws layout (bytes):
//   0       double sqpart[512]       (per-block sum of sq norms)
//   4096    double colpart[512*64]   (per-block col sums, block-major) ->266240
//   266240  float  cs                (exp2 scale)
//   276480  float  sq[8192]
//   311296  short  Xh[8192*64]       (bf16, row-major)
// No memset: every slot is written before it is read. d_out zeroed by
// scale_kernel (kernel-boundary ordering), pass2 accumulates into it with
// pre-scaled float atomicAdds (no fence, no counter -- R17 lesson: the
// fence+counter protocol costs +15us; bare commutative atomics don't).
//
// bf16-only GEMM (no hi/lo compensation): errL2 std ~0.05 -> grand-sum error
// ~5e-7 vs threshold 3.16e-5 (60x margin). Norms/bandwidth stay exact.
// 1/BATCH^2 = 2^-24: scaling each partial is EXACT in fp32; atomic-order
// accumulation error ~2.5e-7.
// R14 lesson: never __threadfence() on the all-threads path (L2 storm).

#if defined(__has_builtin)
#if __has_builtin(__builtin_amdgcn_exp2f)
#define EXP2F(x) __builtin_amdgcn_exp2f(x)
#endif
#endif
#ifndef EXP2F
#define EXP2F(x) exp2f(x)
#endif

typedef __attribute__((ext_vector_type(8))) short bf16x8;
typedef __attribute__((ext_vector_type(4))) float f32x4;
typedef __attribute__((ext_vector_type(2))) float f32x2;
typedef __attribute__((ext_vector_type(4))) short s16x4;

__device__ inline short f2bf_rn(float x) {
    unsigned u = __float_as_uint(x);
    unsigned r = (u + 0x7fffu + ((u >> 16) & 1u)) >> 16;
    return (short)r;
}

// pass1: fp32 -> bf16 (once), row sq-norms (exact fp32), per-block col/sq
// partials stored to memory. 512 blocks -> 1 group-iter per wave.
__global__ __launch_bounds__(256) void pass1_kernel(const float* __restrict__ src,
                                                    const float* __restrict__ tgt,
                                                    double* __restrict__ sqpart,
                                                    double* __restrict__ colpart,
                                                    float* __restrict__ sqbuf,
                                                    short* __restrict__ Xh) {
    __shared__ double cred[4][64];
    __shared__ double sred[4];
    const int lane = threadIdx.x & 63;
    const int wv = threadIdx.x >> 6;
    const int sub = lane >> 4;
    const int k4 = (lane & 15) << 2;
    const int gw = blockIdx.x * 4 + wv;
    const int numWaves = P1_BLOCKS * 4;

    double colacc[4] = {0.0, 0.0, 0.0, 0.0};
    double sqacc = 0.0;

    for (int g = gw; g < N_TOTAL / 4; g += numWaves) {
        int r = g * 4 + sub;
        const float* row = (r < BATCH) ? (src + (size_t)r * DIMS)
                                       : (tgt + (size_t)(r - BATCH) * DIMS);
        float4 v = *(const float4*)(row + k4);
        float xs[4] = {v.x, v.y, v.z, v.w};
        s16x4 h;
        float ssum = 0.f;
        #pragma unroll
        for (int i = 0; i < 4; ++i) {
            h[i] = f2bf_rn(xs[i]);
            colacc[i] += (double)xs[i];
            ssum = fmaf(xs[i], xs[i], ssum);
        }
        *(s16x4*)(Xh + (size_t)r * DIMS + k4) = h;
        ssum += __shfl_xor(ssum, 1, 64);
        ssum += __shfl_xor(ssum, 2, 64);
        ssum += __shfl_xor(ssum, 4, 64);
        ssum += __shfl_xor(ssum, 8, 64);
        if ((lane & 15) == 0) { sqbuf[r] = ssum; sqacc += (double)ssum; }
    }
    #pragma unroll
    for (int i = 0; i < 4; ++i) {
        colacc[i] += __shfl_xor(colacc[i], 16, 64);
        colacc[i] += __shfl_xor(colacc[i], 32, 64);
    }
    sqacc += __shfl_xor(sqacc, 16, 64);
    sqacc += __shfl_xor(sqacc, 32, 64);
    if (lane < 16) {
        #pragma unroll
        for (int i = 0; i < 4; ++i) cred[wv][lane * 4 + i] = colacc[i];
    }
    if (lane == 0) sred[wv] = sqacc;
    __syncthreads();
    if (wv == 0) {
        double c = (cred[0][lane] + cred[1][lane]) + (cred[2][lane] + cred[3][lane]);
        colpart[(size_t)blockIdx.x * 64 + lane] = c;     // coalesced store
        if (lane == 0)
            sqpart[blockIdx.x] = (sred[0] + sred[1]) + (sred[2] + sred[3]);
    }
}

// 512 threads (8 waves): reduce 512 per-block partials -> scale; zero d_out
// (poisoned 0xAA by harness) so pass2 can accumulate into it atomically.
__global__ __launch_bounds__(512) void scale_kernel(const double* __restrict__ sqpart,
                                                    const double* __restrict__ colpart,
                                                    float* __restrict__ csp,
                                                    float* __restrict__ out) {
    __shared__ double cred[8][64];
    __shared__ double sred[8];
    const int t = threadIdx.x;
    const int lane = t & 63, w = t >> 6;
    if (t == 0) out[0] = 0.f;

    double colacc = 0.0;
    #pragma unroll 8
    for (int b = w; b < P1_BLOCKS; b += 8)
        colacc += colpart[(size_t)b * 64 + lane];    // coalesced per wave
    cred[w][lane] = colacc;

    double sacc = sqpart[t];                          // 512 threads, 512 values
    #pragma unroll
    for (int off = 32; off > 0; off >>= 1) sacc += __shfl_xor(sacc, off, 64);
    if (lane == 0) sred[w] = sacc;
    __syncthreads();

    if (w == 0) {
        double colsum = ((cred[0][lane] + cred[1][lane]) + (cred[2][lane] + cred[3][lane]))
                      + ((cred[4][lane] + cred[5][lane]) + (cred[6][lane] + cred[7][lane]));
        double vv = colsum * colsum;
        #pragma unroll
        for (int off = 32; off > 0; off >>= 1) vv += __shfl_xor(vv, off, 64);
        if (lane == 0) {
            double sq = ((sred[0] + sred[1]) + (sred[2] + sred[3]))
                      + ((sred[4] + sred[5]) + (sred[6] + sred[7]));
            const double n = (double)N_TOTAL;
            double bw0 = (2.0 * n * sq - 2.0 * vv) / (n * n - n) * 0.25;
            csp[0] = (float)(-1.0 / (bw0 * 0.6931471805599453 * 16.0));
        }
    }
}

// pass2: frozen best body (R18). Flat live-only grid of 1088 blocks.
// 512-thread blocks = 8 waves share one LDS B-tile; per tile-iter: 2 global
// A-loads, 8 LDS b128, 8 MFMA, packed-fp32 exp epilogue. Block result is
// scaled by exact 2^-24 and atomically added to out (replaces finalize).
__global__ __launch_bounds__(512) void pass2_kernel(const short* __restrict__ Xh,
                                                    const float* __restrict__ sqbuf,
                                                    const float* __restrict__ csp,
                                                    float* __restrict__ out) {
    // decode flat id: band b (bc=8b+q) has 8 bc x (b+1) segments
    const int f = blockIdx.x;
    int b = 0;
    while (4 * (b + 1) * (b + 2) <= f) ++b;          // <=15 steps
    const int rem = f - 4 * b * (b + 1);
    const int q = rem / (b + 1);
    const int bc = 8 * b + q;
    const int seg = rem - q * (b + 1);
    const int r0 = seg * SEG;
    const int r1 = (bc < r0 + SEG - 1) ? bc : r0 + SEG - 1;

    __shared__ __align__(16) short Bh[64][72];
    __shared__ float s_wred[8];

    const int t = threadIdx.x;
    const int lane = t & 63, w = t >> 6;
    const int strip = w & 3, ts = w >> 2;
    const int quad = lane >> 4, lrow = lane & 15;

    // stage B column-tile into LDS: 512 threads, one shot
    {
        int row = t >> 3;            // 0..63
        int c8 = (t & 7) << 3;       // short offset 0..56
        size_t gsrc = (size_t)(bc * 64 + row) * DIMS + c8;
        *(s16x4*)&Bh[row][c8]     = *(const s16x4*)(Xh + gsrc);
        *(s16x4*)&Bh[row][c8 + 4] = *(const s16x4*)(Xh + gsrc + 4);
    }
    const float cs = csp[0];
    const float c2 = -2.f * cs;
    const f32x2 c2v = (f32x2){c2, c2};
    f32x2 sbj[4];
    #pragma unroll
    for (int j = 0; j < 4; ++j) {
        float s = sqbuf[bc * 64 + j * 16 + lrow] * cs;
        sbj[j] = (f32x2){s, s};
    }
    __syncthreads();

    const size_t aoff = (size_t)(strip * 16 + lrow) * DIMS + quad * 8;

    float facc = 0.f;

    for (int r = r0 + ts; r <= r1; r += 2) {
        const size_t abase = (size_t)r * 64 * DIMS + aoff;
        bf16x8 ah0 = *(const bf16x8*)(Xh + abase);
        bf16x8 ah1 = *(const bf16x8*)(Xh + abase + 32);
        float4 csa = *(const float4*)(sqbuf + r * 64 + strip * 16 + quad * 4);

        f32x4 acc[4];
        #pragma unroll
        for (int j = 0; j < 4; ++j) acc[j] = (f32x4){0.f, 0.f, 0.f, 0.f};
        #pragma unroll
        for (int j = 0; j < 4; ++j) {
            const int brow = j * 16 + lrow;
            const int bcol = quad * 8;
            bf16x8 bh0 = *(const bf16x8*)&Bh[brow][bcol];
            bf16x8 bh1 = *(const bf16x8*)&Bh[brow][bcol + 32];
            acc[j] = __builtin_amdgcn_mfma_f32_16x16x32_bf16(ah0, bh0, acc[j], 0, 0, 0);
            acc[j] = __builtin_amdgcn_mfma_f32_16x16x32_bf16(ah1, bh1, acc[j], 0, 0, 0);
        }

        const f32x2 sa01 = (f32x2){csa.x * cs, csa.y * cs};
        const f32x2 sa23 = (f32x2){csa.z * cs, csa.w * cs};
        f32x2 lsum2 = (f32x2){0.f, 0.f};
        #pragma unroll
        for (int j = 0; j < 4; ++j) {
            // t0 = -L2/(16*bw0*ln2) on element pairs (packed fp32)
            f32x2 a01 = (f32x2){acc[j][0], acc[j][1]};
            f32x2 a23 = (f32x2){acc[j][2], acc[j][3]};
            f32x2 t01 = a01 * c2v + (sa01 + sbj[j]);
            f32x2 t23 = a23 * c2v + (sa23 + sbj[j]);
            // 1 exp2 + 4 packed squarings = all 5 bandwidth kernels
            f32x2 e4a = (f32x2){EXP2F(t01[0]), EXP2F(t01[1])};
            f32x2 e4b = (f32x2){EXP2F(t23[0]), EXP2F(t23[1])};
            f32x2 e3a = e4a * e4a, e3b = e4b * e4b;
            f32x2 e2a = e3a * e3a, e2b = e3b * e3b;
            f32x2 e1a = e2a * e2a, e1b = e2b * e2b;
            f32x2 e0a = e1a * e1a, e0b = e1b * e1b;
            lsum2 += ((e0a + e1a) + (e2a + e3a)) + e4a;
            lsum2 += ((e0b + e1b) + (e2b + e3b)) + e4b;
        }
        float lsum = lsum2[0] + lsum2[1];
        float sgn = ((r < 64) == (bc < 64)) ? 1.f : -1.f;
        float wt  = (r == bc) ? 1.f : 2.f;
        facc = fmaf(lsum, sgn * wt, facc);
    }

    #pragma unroll
    for (int off = 32; off > 0; off >>= 1) facc += __shfl_xor(facc, off, 64);
    if (lane == 0) s_wred[w] = facc;
    __syncthreads();
    if (t == 0) {
        float bsum = ((s_wred[0] + s_wred[1]) + (s_wred[2] + s_wred[3]))
                   + ((s_wred[4] + s_wred[5]) + (s_wred[6] + s_wred[7]));
        // 1/BATCH^2 = 2^-24: exact fp32 scaling; bare atomic, no fence
        atomicAdd(out, bsum * 5.9604644775390625e-08f);
    }
}

extern "C" void kernel_launch(void* const* d_in, const int* in_sizes, int n_in,
                              void* d_out, int out_size, void* d_ws, size_t ws_size,
                              hipStream_t stream) {
    const float* src = (const float*)d_in[0];
    const float* tgt = (const float*)d_in[1];
    char* ws = (char*)d_ws;
    double* sqpart  = (double*)ws;
    double* colpart = (double*)(ws + 4096);
    float*  csp     = (float*)(ws + 266240);
    float*  sqbuf   = (float*)(ws + 276480);
    short*  Xh      = (short*)(ws + 311296);

    // no memset: every ws slot is written before it is read

    pass1_kernel<<<P1_BLOCKS, 256, 0, stream>>>(src, tgt, sqpart, colpart,
                                                sqbuf, Xh);
    scale_kernel<<<1, 512, 0, stream>>>(sqpart, colpart, csp, (float*)d_out);

    pass2_kernel<<<P2_BLOCKS, 512, 0, stream>>>(Xh, sqbuf, csp, (float*)d_out);
}